// Round 2
// baseline (1170.955 us; speedup 1.0000x reference)
//
#include <hip/hip_runtime.h>
#include <stdint.h>

// Problem constants (B,S,H,W,L) = (16,2048,512,4,2)
#define Bx   16
#define Sx   2048
#define Hx   512
#define Lx   2
#define PHx  2056            // S + 2W
#define Mx   32768           // B*S

typedef float f32x4  __attribute__((ext_vector_type(4)));
typedef __bf16 bf16x8 __attribute__((ext_vector_type(8)));
typedef unsigned short u16x8 __attribute__((ext_vector_type(8)));

typedef __attribute__((address_space(1))) void gvoid_t;
typedef __attribute__((address_space(3))) void lvoid_t;

__device__ __forceinline__ unsigned short f2bf(float f) {
  uint32_t u = __float_as_uint(f);
  u += 0x7FFFu + ((u >> 16) & 1u);   // round-to-nearest-even
  return (unsigned short)(u >> 16);
}

// LDS swizzle: element offset XOR ((row&7)<<3)  == byte ^ ((row&7)<<4).
// Spreads the 16 fc-lanes of a frag ds_read_b128 across 8 bank-quads (2-way,
// free) instead of 16-way at BK=64 linear. Applied as: linear DMA dest +
// pre-swizzled GLOBAL source col (rule #21), swizzled read addr.

// ---------------------------------------------------------------------------
// padded[b, r, h]: r<4 -> left_padding, 4..2051 -> inputs, 2052..2055 -> right
// ---------------------------------------------------------------------------
__global__ __launch_bounds__(256) void build_padded_k(
    const float* __restrict__ inp, const float* __restrict__ lp,
    const float* __restrict__ rp, unsigned short* __restrict__ padded) {
  int64_t idx = ((int64_t)blockIdx.x * 256 + threadIdx.x) * 8;  // < 16*2056*512
  int h = (int)(idx & 511);
  int64_t rowi = idx >> 9;                 // b*2056 + r
  int r = (int)(rowi % 2056);
  int b = (int)(rowi / 2056);
  const float* src;
  if (r < 4)          src = lp + r * 512 + h;
  else if (r < 2052)  src = inp + ((int64_t)b * 2048 + (r - 4)) * 512 + h;
  else                src = rp + (r - 2052) * 512 + h;
  float4 u = ((const float4*)src)[0];
  float4 w = ((const float4*)src)[1];
  u16x8 o;
  o[0] = f2bf(u.x); o[1] = f2bf(u.y); o[2] = f2bf(u.z); o[3] = f2bf(u.w);
  o[4] = f2bf(w.x); o[5] = f2bf(w.y); o[6] = f2bf(w.z); o[7] = f2bf(w.w);
  *(u16x8*)(padded + idx) = o;
}

// ---------------------------------------------------------------------------
// Weight prep: bf16 [N][K] transpose via LDS 32x32 tiles.
// ---------------------------------------------------------------------------
__global__ __launch_bounds__(256) void prep_weights_k(
    const float* __restrict__ Wl, const float* __restrict__ Wr,
    const float* __restrict__ lw1, const float* __restrict__ lw2,
    const float* __restrict__ rw1, const float* __restrict__ rw2,
    unsigned short* __restrict__ Wlt, unsigned short* __restrict__ Wrt,
    unsigned short* __restrict__ lw1t, unsigned short* __restrict__ lw2t,
    unsigned short* __restrict__ rw1t, unsigned short* __restrict__ rw2t) {
  __shared__ unsigned short tl[32][36];
  int b = blockIdx.x;
  const float* src; unsigned short* dst; int K, tk, tn;
  if (b < 2048) {
    src = (b < 1024) ? Wl : Wr;
    dst = (b < 1024) ? Wlt : Wrt;
    int t = b & 1023; tk = t >> 4; tn = t & 15; K = 2048;
  } else {
    int b2 = b - 2048;
    int mat = b2 >> 8;  // 0..7
    const float* srcs[8] = {lw1, lw1 + 262144, lw2, lw2 + 262144,
                            rw1, rw1 + 262144, rw2, rw2 + 262144};
    unsigned short* dsts[8] = {lw1t, lw1t + 262144, lw2t, lw2t + 262144,
                               rw1t, rw1t + 262144, rw2t, rw2t + 262144};
    src = srcs[mat]; dst = dsts[mat];
    int tt = b2 & 255; tk = tt >> 4; tn = tt & 15; K = 512;
  }
  int t = threadIdx.x;
  int rr = t >> 3, c4 = (t & 7) * 4;
  float4 v = *(const float4*)(src + (int64_t)(tk * 32 + rr) * 512 + tn * 32 + c4);
  tl[c4 + 0][rr] = f2bf(v.x);
  tl[c4 + 1][rr] = f2bf(v.y);
  tl[c4 + 2][rr] = f2bf(v.z);
  tl[c4 + 3][rr] = f2bf(v.w);
  __syncthreads();
  int nn = t >> 3, k4 = (t & 7) * 4;
  ushort4 o = {tl[nn][k4], tl[nn][k4 + 1], tl[nn][k4 + 2], tl[nn][k4 + 3]};
  *(ushort4*)(dst + (int64_t)(tn * 32 + nn) * K + tk * 32 + k4) = o;
}

// ---------------------------------------------------------------------------
// GEMM (producer): C[M,512 cols of side z] = epilogue(A @ Bt^T + bias).
// grid (256, 4, 2). 128x128 tile, BK=64, 4 waves, 4x4x2 mfma 16x16x32.
// LDS tiles [128][64] bf16, XOR-swizzled (see top).
// MODE 0: v = relu(acc+bias); C[m*1024 + z*512 + n] = v       (projection)
// MODE 2: v = C[..] + acc + bias; C[..] = v; out0p[s*16384+b*1024+z*512+n] = v
// STATS: per-row (sum, sumsq) of v -> P[(z*4+nb)*M + m][2]  (non-atomic)
// ---------------------------------------------------------------------------
template <int MODE, bool STATS>
__global__ __launch_bounds__(256) void gemm_k(
    const unsigned short* __restrict__ A0, const unsigned short* __restrict__ A1,
    int64_t a_bstride, int a_off_per_z, int K,
    const unsigned short* __restrict__ Bt0, const unsigned short* __restrict__ Bt1,
    const float* __restrict__ bias0, const float* __restrict__ bias1,
    float* __restrict__ C, float* __restrict__ out0p, float* __restrict__ P) {
  __shared__ unsigned short sA[128 * 64];
  __shared__ unsigned short sB[128 * 64];
  __shared__ float sls[128][2][2];
  const int tid  = threadIdx.x;
  const int lane = tid & 63;
  const int wave = tid >> 6;
  const int m0 = blockIdx.x * 128;
  const int n0 = blockIdx.y * 128;
  const int z  = blockIdx.z;
  const int wm = (wave >> 1) * 64;
  const int wn = (wave & 1) * 64;
  const int fr = lane >> 4;
  const int fc = lane & 15;
  const int swf = (fc & 7) << 3;      // frag-read swizzle term (row&7 == fc&7)

  const unsigned short* A  = z ? A1 : A0;
  const unsigned short* Bt = z ? Bt1 : Bt0;
  const float* bias = z ? bias1 : bias0;
  const int a_off = z * a_off_per_z;
  const int c_off = z * 512;

  const unsigned short* Ablk =
      A + (int64_t)(m0 >> 11) * a_bstride + (int64_t)(m0 & 2047) * 512 + a_off;
  const unsigned short* Bblk = Bt + (int64_t)n0 * K;

  f32x4 acc[4][4] = {};

  for (int k0 = 0; k0 < K; k0 += 64) {
#pragma unroll
    for (int r = 0; r < 4; r++) {
      const int tt = tid + r * 256;          // 0..1023
      const int ar = tt >> 3;                // 0..127
      const int ac = (tt & 7) * 8;           // 0..56
      const int acs = ac ^ ((ar & 7) << 3);  // pre-swizzled source col
      __builtin_amdgcn_global_load_lds(
          (gvoid_t*)(Ablk + (int64_t)ar * 512 + k0 + acs),
          (lvoid_t*)(sA + tt * 8), 16, 0, 0);
      __builtin_amdgcn_global_load_lds(
          (gvoid_t*)(Bblk + (int64_t)ar * K + k0 + acs),
          (lvoid_t*)(sB + tt * 8), 16, 0, 0);
    }
    __syncthreads();

#pragma unroll
    for (int kk = 0; kk < 2; kk++) {
      bf16x8 af[4], bf[4];
#pragma unroll
      for (int i = 0; i < 4; i++)
        af[i] = *(const bf16x8*)(sA + (((wm + i * 16 + fc) * 64 + kk * 32 + fr * 8) ^ swf));
#pragma unroll
      for (int j = 0; j < 4; j++)
        bf[j] = *(const bf16x8*)(sB + (((wn + j * 16 + fc) * 64 + kk * 32 + fr * 8) ^ swf));
#pragma unroll
      for (int i = 0; i < 4; i++)
#pragma unroll
        for (int j = 0; j < 4; j++)
          acc[i][j] = __builtin_amdgcn_mfma_f32_16x16x32_bf16(af[i], bf[j], acc[i][j], 0, 0, 0);
    }
    __syncthreads();
  }

  // epilogue: acc[i][j][r] -> row m0+wm+i*16+fr*4+r, col n0+wn+j*16+fc
  int col[4];
  float bv[4];
#pragma unroll
  for (int j = 0; j < 4; j++) {
    col[j] = n0 + wn + j * 16 + fc;
    bv[j] = bias[col[j]];
  }
  const int b_idx = m0 >> 11;
#pragma unroll
  for (int i = 0; i < 4; i++) {
#pragma unroll
    for (int r = 0; r < 4; r++) {
      const int m = m0 + wm + i * 16 + fr * 4 + r;
      const int64_t base = (int64_t)m * 1024 + c_off;
      float vs[4];
      if (MODE == 0) {
#pragma unroll
        for (int j = 0; j < 4; j++) {
          float v = acc[i][j][r] + bv[j];
          v = v > 0.f ? v : 0.f;
          C[base + col[j]] = v;
          vs[j] = v;
        }
      } else {
        const int s = m & 2047;
        const int64_t obase = (int64_t)s * 16384 + (int64_t)b_idx * 1024 + c_off;
#pragma unroll
        for (int j = 0; j < 4; j++) {
          float v = C[base + col[j]] + acc[i][j][r] + bv[j];
          C[base + col[j]] = v;
          out0p[obase + col[j]] = v;
          vs[j] = v;
        }
      }
      if (STATS) {
        float s1 = vs[0] + vs[1] + vs[2] + vs[3];
        float s2 = vs[0] * vs[0] + vs[1] * vs[1] + vs[2] * vs[2] + vs[3] * vs[3];
#pragma unroll
        for (int o = 1; o < 16; o <<= 1) {
          s1 += __shfl_xor(s1, o);
          s2 += __shfl_xor(s2, o);
        }
        if (fc == 0) {
          int li = (wave >> 1) * 64 + i * 16 + fr * 4 + r;
          sls[li][wave & 1][0] = s1;
          sls[li][wave & 1][1] = s2;
        }
      }
    }
  }
  if (STATS) {
    __syncthreads();
    int li = tid >> 1, comp = tid & 1;
    float v = sls[li][0][comp] + sls[li][1][comp];
    P[(((int64_t)z * 4 + blockIdx.y) * Mx + m0 + li) * 2 + comp] = v;
  }
}

// ---------------------------------------------------------------------------
// FF first GEMM with fused LayerNorm on A-load:
// hidden[z][m][n] = relu( LN(state_row_m, side z) @ w1^T + b1 )
// A staged via VGPRs (fp32 state -> LN -> bf16 -> swizzled ds_write).
// B staged via global_load_lds (pre-swizzled source). K = 512, BK = 64.
// ---------------------------------------------------------------------------
__global__ __launch_bounds__(256) void gemm_ln_k(
    const float* __restrict__ state, const float* __restrict__ P,
    const float* __restrict__ g0, const float* __restrict__ g1p,
    const float* __restrict__ be0, const float* __restrict__ be1,
    const unsigned short* __restrict__ Bt0, const unsigned short* __restrict__ Bt1,
    const float* __restrict__ bias0, const float* __restrict__ bias1,
    unsigned short* __restrict__ hidden) {
  __shared__ unsigned short sA[128 * 64];
  __shared__ unsigned short sB[128 * 64];
  const int tid  = threadIdx.x;
  const int lane = tid & 63;
  const int wave = tid >> 6;
  const int m0 = blockIdx.x * 128;
  const int n0 = blockIdx.y * 128;
  const int z  = blockIdx.z;
  const int wm = (wave >> 1) * 64;
  const int wn = (wave & 1) * 64;
  const int fr = lane >> 4;
  const int fc = lane & 15;
  const int swf = (fc & 7) << 3;

  const unsigned short* Bt = z ? Bt1 : Bt0;
  const float* bias = z ? bias1 : bias0;
  const float* g    = z ? g1p : g0;
  const float* be   = z ? be1 : be0;
  const int c_off = z * 512;
  const unsigned short* Bblk = Bt + (int64_t)n0 * 512;

  // A-staging mapping: thread -> (row, 32-col half), in two 16-col sub-chunks
  const int row  = tid >> 1;
  const int half = tid & 1;
  const int m = m0 + row;
  const int swr = (row & 7) << 3;
  const float* srcrow = state + (int64_t)m * 1024 + c_off;

  // row stats: combine 4 n-block partials
  float s1 = 0.f, s2 = 0.f;
#pragma unroll
  for (int nb = 0; nb < 4; nb++) {
    s1 += P[(((int64_t)z * 4 + nb) * Mx + m) * 2 + 0];
    s2 += P[(((int64_t)z * 4 + nb) * Mx + m) * 2 + 1];
  }
  const float mean = s1 * (1.0f / 512.0f);
  const float rstd = rsqrtf(s2 * (1.0f / 512.0f) - mean * mean + 1e-5f);

  f32x4 acc[4][4] = {};

  for (int k0 = 0; k0 < 512; k0 += 64) {
#pragma unroll
    for (int r = 0; r < 4; r++) {
      const int tt = tid + r * 256;
      const int br = tt >> 3;
      const int bc = (tt & 7) * 8;
      const int bcs = bc ^ ((br & 7) << 3);
      __builtin_amdgcn_global_load_lds(
          (gvoid_t*)(Bblk + (int64_t)br * 512 + k0 + bcs),
          (lvoid_t*)(sB + tt * 8), 16, 0, 0);
    }

#pragma unroll
    for (int sc = 0; sc < 2; sc++) {
      const int cb = half * 32 + sc * 16;       // col offset within BK=64 tile
      const float* xp = srcrow + k0 + cb;
      const float* gp = g + k0 + cb;
      const float* bp = be + k0 + cb;
      float xs[16], gs[16], bs[16];
      *(float4*)(xs + 0)  = ((const float4*)xp)[0];
      *(float4*)(xs + 4)  = ((const float4*)xp)[1];
      *(float4*)(xs + 8)  = ((const float4*)xp)[2];
      *(float4*)(xs + 12) = ((const float4*)xp)[3];
      *(float4*)(gs + 0)  = ((const float4*)gp)[0];
      *(float4*)(gs + 4)  = ((const float4*)gp)[1];
      *(float4*)(gs + 8)  = ((const float4*)gp)[2];
      *(float4*)(gs + 12) = ((const float4*)gp)[3];
      *(float4*)(bs + 0)  = ((const float4*)bp)[0];
      *(float4*)(bs + 4)  = ((const float4*)bp)[1];
      *(float4*)(bs + 8)  = ((const float4*)bp)[2];
      *(float4*)(bs + 12) = ((const float4*)bp)[3];
      u16x8 o0, o1;
#pragma unroll
      for (int t = 0; t < 8; t++)
        o0[t] = f2bf((xs[t] - mean) * rstd * gs[t] + bs[t]);
#pragma unroll
      for (int t = 0; t < 8; t++)
        o1[t] = f2bf((xs[t + 8] - mean) * rstd * gs[t + 8] + bs[t + 8]);
      *(u16x8*)(sA + ((row * 64 + cb) ^ swr))     = o0;
      *(u16x8*)(sA + ((row * 64 + cb + 8) ^ swr)) = o1;
    }
    __syncthreads();

#pragma unroll
    for (int kk = 0; kk < 2; kk++) {
      bf16x8 af[4], bf[4];
#pragma unroll
      for (int i = 0; i < 4; i++)
        af[i] = *(const bf16x8*)(sA + (((wm + i * 16 + fc) * 64 + kk * 32 + fr * 8) ^ swf));
#pragma unroll
      for (int j = 0; j < 4; j++)
        bf[j] = *(const bf16x8*)(sB + (((wn + j * 16 + fc) * 64 + kk * 32 + fr * 8) ^ swf));
#pragma unroll
      for (int i = 0; i < 4; i++)
#pragma unroll
        for (int j = 0; j < 4; j++)
          acc[i][j] = __builtin_amdgcn_mfma_f32_16x16x32_bf16(af[i], bf[j], acc[i][j], 0, 0, 0);
    }
    __syncthreads();
  }

  unsigned short* Cb = hidden + (int64_t)z * Mx * 512;
  int col[4];
  float bv[4];
#pragma unroll
  for (int j = 0; j < 4; j++) {
    col[j] = n0 + wn + j * 16 + fc;
    bv[j] = bias[col[j]];
  }
#pragma unroll
  for (int i = 0; i < 4; i++) {
#pragma unroll
    for (int r = 0; r < 4; r++) {
      const int mm = m0 + wm + i * 16 + fr * 4 + r;
      const int64_t base = (int64_t)mm * 512;
#pragma unroll
      for (int j = 0; j < 4; j++) {
        float v = acc[i][j][r] + bv[j];
        Cb[base + col[j]] = f2bf(v > 0.f ? v : 0.f);
      }
    }
  }
}

// ---------------------------------------------------------------------------
extern "C" void kernel_launch(void* const* d_in, const int* in_sizes, int n_in,
                              void* d_out, int out_size, void* d_ws, size_t ws_size,
                              hipStream_t stream) {
  const float* inputs = (const float*)d_in[0];
  const float* lp     = (const float*)d_in[1];
  const float* rp     = (const float*)d_in[2];
  const float* Wl     = (const float*)d_in[3];
  const float* bl     = (const float*)d_in[4];
  const float* Wr     = (const float*)d_in[5];
  const float* br     = (const float*)d_in[6];
  const float* lw1    = (const float*)d_in[7];
  const float* lb1    = (const float*)d_in[8];
  const float* lw2    = (const float*)d_in[9];
  const float* lb2    = (const float*)d_in[10];
  const float* lg     = (const float*)d_in[11];
  const float* lbeta  = (const float*)d_in[12];
  const float* rw1    = (const float*)d_in[13];
  const float* rb1    = (const float*)d_in[14];
  const float* rw2    = (const float*)d_in[15];
  const float* rb2    = (const float*)d_in[16];
  const float* rg     = (const float*)d_in[17];
  const float* rbeta  = (const float*)d_in[18];

  float* out0 = (float*)d_out;                              // all_layers [L,S,B,2H]
  float* out1 = out0 + (int64_t)Lx * Sx * Bx * 1024;        // last_layers (lo/ro state)

  char* w = (char*)d_ws;
  auto take = [&](size_t n) { char* p = w; w += (n + 255) & ~(size_t)255; return p; };
  unsigned short* padded = (unsigned short*)take((size_t)Bx * PHx * Hx * 2);
  unsigned short* Wlt    = (unsigned short*)take(2048ull * 512 * 2);
  unsigned short* Wrt    = (unsigned short*)take(2048ull * 512 * 2);
  unsigned short* lw1t   = (unsigned short*)take((size_t)Lx * 512 * 512 * 2);
  unsigned short* lw2t   = (unsigned short*)take((size_t)Lx * 512 * 512 * 2);
  unsigned short* rw1t   = (unsigned short*)take((size_t)Lx * 512 * 512 * 2);
  unsigned short* rw2t   = (unsigned short*)take((size_t)Lx * 512 * 512 * 2);
  unsigned short* hidden = (unsigned short*)take((size_t)2 * Mx * 512 * 2);
  float*          Pst    = (float*)take((size_t)2 * 4 * Mx * 2 * 4);

  build_padded_k<<<8224, 256, 0, stream>>>(inputs, lp, rp, padded);
  prep_weights_k<<<4096, 256, 0, stream>>>(Wl, Wr, lw1, lw2, rw1, rw2,
                                           Wlt, Wrt, lw1t, lw2t, rw1t, rw2t);

  dim3 gg(256, 4, 2);
  // projections (z=0 left a_off=0, z=1 right a_off=2560), with LN stats
  gemm_k<0, true><<<gg, 256, 0, stream>>>(
      padded, padded, (int64_t)PHx * 512, 5 * 512, 2048,
      Wlt, Wrt, bl, br, out1, nullptr, Pst);

  for (int i = 0; i < Lx; i++) {
    gemm_ln_k<<<gg, 256, 0, stream>>>(
        out1, Pst, lg + i * 512, rg + i * 512, lbeta + i * 512, rbeta + i * 512,
        lw1t + (int64_t)i * 262144, rw1t + (int64_t)i * 262144,
        lb1 + i * 512, rb1 + i * 512, hidden);
    if (i == 0) {
      gemm_k<2, true><<<gg, 256, 0, stream>>>(
          hidden, hidden + (int64_t)Mx * 512, (int64_t)2048 * 512, 0, 512,
          lw2t, rw2t, lb2, rb2, out1, out0, Pst);
    } else {
      gemm_k<2, false><<<gg, 256, 0, stream>>>(
          hidden, hidden + (int64_t)Mx * 512, (int64_t)2048 * 512, 0, 512,
          lw2t + (int64_t)i * 262144, rw2t + (int64_t)i * 262144,
          lb2 + i * 512, rb2 + i * 512, out1,
          out0 + (int64_t)i * Sx * Bx * 1024, nullptr);
    }
  }
}

// Round 4
// 1079.978 us; speedup vs baseline: 1.0842x; 1.0842x over previous
//
#include <hip/hip_runtime.h>
#include <stdint.h>

// Problem constants (B,S,H,W,L) = (16,2048,512,4,2)
#define Bx   16
#define Sx   2048
#define Hx   512
#define Lx   2
#define PHx  2056            // S + 2W
#define Mx   32768           // B*S

typedef float f32x4  __attribute__((ext_vector_type(4)));
typedef __bf16 bf16x8 __attribute__((ext_vector_type(8)));
typedef unsigned short u16x8 __attribute__((ext_vector_type(8)));

typedef __attribute__((address_space(1))) void gvoid_t;
typedef __attribute__((address_space(3))) void lvoid_t;

__device__ __forceinline__ unsigned short f2bf(float f) {
  uint32_t u = __float_as_uint(f);
  u += 0x7FFFu + ((u >> 16) & 1u);   // round-to-nearest-even
  return (unsigned short)(u >> 16);
}

// Pinned barrier: s_barrier is IntrNoMem (NOT a memory fence) — without the
// sched_barrier(0) brackets the scheduler may hoist a global_load_lds issue
// across it into a region where other waves still read that LDS slot
// (round-3 replay race). Rule #18 fence.
__device__ __forceinline__ void sbar() {
  __builtin_amdgcn_sched_barrier(0);
  __builtin_amdgcn_s_barrier();
  __builtin_amdgcn_sched_barrier(0);
}
#define VMCNT(n) do {                                        \
    __builtin_amdgcn_sched_barrier(0);                       \
    asm volatile("s_waitcnt vmcnt(" #n ")" ::: "memory");    \
    __builtin_amdgcn_sched_barrier(0);                       \
  } while (0)

// ---------------------------------------------------------------------------
// padded[b, r, h]: r<4 -> left_padding, 4..2051 -> inputs, 2052..2055 -> right
// ---------------------------------------------------------------------------
__global__ __launch_bounds__(256) void build_padded_k(
    const float* __restrict__ inp, const float* __restrict__ lp,
    const float* __restrict__ rp, unsigned short* __restrict__ padded) {
  int64_t idx = ((int64_t)blockIdx.x * 256 + threadIdx.x) * 8;  // < 16*2056*512
  int h = (int)(idx & 511);
  int64_t rowi = idx >> 9;                 // b*2056 + r
  int r = (int)(rowi % 2056);
  int b = (int)(rowi / 2056);
  const float* src;
  if (r < 4)          src = lp + r * 512 + h;
  else if (r < 2052)  src = inp + ((int64_t)b * 2048 + (r - 4)) * 512 + h;
  else                src = rp + (r - 2052) * 512 + h;
  float4 u = ((const float4*)src)[0];
  float4 w = ((const float4*)src)[1];
  u16x8 o;
  o[0] = f2bf(u.x); o[1] = f2bf(u.y); o[2] = f2bf(u.z); o[3] = f2bf(u.w);
  o[4] = f2bf(w.x); o[5] = f2bf(w.y); o[6] = f2bf(w.z); o[7] = f2bf(w.w);
  *(u16x8*)(padded + idx) = o;
}

// ---------------------------------------------------------------------------
// Weight prep: bf16 [N][K] transpose via LDS 32x32 tiles.
// ---------------------------------------------------------------------------
__global__ __launch_bounds__(256) void prep_weights_k(
    const float* __restrict__ Wl, const float* __restrict__ Wr,
    const float* __restrict__ lw1, const float* __restrict__ lw2,
    const float* __restrict__ rw1, const float* __restrict__ rw2,
    unsigned short* __restrict__ Wlt, unsigned short* __restrict__ Wrt,
    unsigned short* __restrict__ lw1t, unsigned short* __restrict__ lw2t,
    unsigned short* __restrict__ rw1t, unsigned short* __restrict__ rw2t) {
  __shared__ unsigned short tl[32][36];
  int b = blockIdx.x;
  const float* src; unsigned short* dst; int K, tk, tn;
  if (b < 2048) {
    src = (b < 1024) ? Wl : Wr;
    dst = (b < 1024) ? Wlt : Wrt;
    int t = b & 1023; tk = t >> 4; tn = t & 15; K = 2048;
  } else {
    int b2 = b - 2048;
    int mat = b2 >> 8;  // 0..7
    const float* srcs[8] = {lw1, lw1 + 262144, lw2, lw2 + 262144,
                            rw1, rw1 + 262144, rw2, rw2 + 262144};
    unsigned short* dsts[8] = {lw1t, lw1t + 262144, lw2t, lw2t + 262144,
                               rw1t, rw1t + 262144, rw2t, rw2t + 262144};
    src = srcs[mat]; dst = dsts[mat];
    int tt = b2 & 255; tk = tt >> 4; tn = tt & 15; K = 512;
  }
  int t = threadIdx.x;
  int rr = t >> 3, c4 = (t & 7) * 4;
  float4 v = *(const float4*)(src + (int64_t)(tk * 32 + rr) * 512 + tn * 32 + c4);
  tl[c4 + 0][rr] = f2bf(v.x);
  tl[c4 + 1][rr] = f2bf(v.y);
  tl[c4 + 2][rr] = f2bf(v.z);
  tl[c4 + 3][rr] = f2bf(v.w);
  __syncthreads();
  int nn = t >> 3, k4 = (t & 7) * 4;
  ushort4 o = {tl[nn][k4], tl[nn][k4 + 1], tl[nn][k4 + 2], tl[nn][k4 + 3]};
  *(ushort4*)(dst + (int64_t)(tn * 32 + nn) * K + tk * 32 + k4) = o;
}

// ---------------------------------------------------------------------------
// Projection GEMM, 8-phase 256x256 schedule (T2+T3+T4+T5), sched-pinned.
// C[m,z*512+n] = relu(A_window @ W^T + bias), per-row stats -> P (4 partials).
// 512 threads (8 waves, 2My x 4Nx), BK=64, K=2048 (32 K-tiles, 16 iters).
// LDS: 8 half-tile slots [buf][A/B][half], each 128x64 bf16 = 16KB -> 128KB.
// Swizzle: elem ^= ((row>>2)&1)<<4 (st_16x32, = m201's byte^((byte>>9)&1)<<5);
// applied on global SOURCE col (linear DMA dest, rule #21) and on frag read.
// Stage schedule (iter t, phases p0..p7), slot = buf*4 + isB*2 + half:
//   p0: slot5=b1.Ah1 (tile 2t+1)   p4: slot1=b0.Ah1 (2t+2)
//   p1: slot7=b1.Bh1 (2t+1)        p5: slot3=b0.Bh1 (2t+2)
//   p2: slot0=b0.Ah0 (2t+2)        p6: slot4=b1.Ah0 (2t+3)
//   p3: slot2=b0.Bh0 (2t+2)        p7: slot6=b1.Bh0 (2t+3)
// Waits: vmcnt(4) end of p3 (tile 2t+1 fully landed) and p7 (tile 2t+2);
// last iter: vmcnt(0) at p3. Per-phase stage/read slot sets are disjoint;
// every stage issue is >=1 pinned barrier after its slot's last read.
// ---------------------------------------------------------------------------
__global__ __launch_bounds__(512, 2) void proj8_k(
    const unsigned short* __restrict__ A,
    const unsigned short* __restrict__ Bt0, const unsigned short* __restrict__ Bt1,
    const float* __restrict__ bias0, const float* __restrict__ bias1,
    float* __restrict__ C, float* __restrict__ P) {
  __shared__ unsigned short lds[8][8192];
  const int tid  = threadIdx.x;
  const int lane = tid & 63;
  const int wave = tid >> 6;          // 0..7
  const int wy = wave >> 2;           // 0..1  (M position within quadrant)
  const int wx = wave & 3;            // 0..3  (N position within quadrant)
  const int fr = lane >> 4;
  const int fc = lane & 15;
  const int m0   = blockIdx.x * 256;
  const int nblk = blockIdx.y;        // 0..1 (256-col groups)
  const int z    = blockIdx.z;

  const unsigned short* Bt = z ? Bt1 : Bt0;
  const float* bias = z ? bias1 : bias0;
  const unsigned short* Ablk = A + (int64_t)(m0 >> 11) * ((int64_t)PHx * 512)
                                 + (int64_t)(m0 & 2047) * 512 + z * 2560;
  const unsigned short* Bblk = Bt + (int64_t)nblk * 256 * 2048;

  auto stage = [&](int slot, int isB, int h, int tile) {
#pragma unroll
    for (int L = 0; L < 2; ++L) {
      const int tt = tid + L * 512;          // 0..1023
      const int row = tt >> 3;               // 0..127
      const int chunk = (tt & 7) * 8;        // 0..56
      const int scol = chunk ^ (((row >> 2) & 1) << 4);
      const unsigned short* src = isB
          ? Bblk + (int64_t)(h * 128 + row) * 2048 + tile * 64 + scol
          : Ablk + (int64_t)(h * 128 + row) * 512  + tile * 64 + scol;
      __builtin_amdgcn_global_load_lds((gvoid_t*)src,
          (lvoid_t*)(&lds[slot][tt * 8]), 16, 0, 0);
    }
  };
  auto rdA = [&](int buf, int h, int i, int kk) -> bf16x8 {
    const int row = wy * 64 + i * 16 + fc;
    const int e = (row * 64 + kk * 32 + fr * 8) ^ (((row >> 2) & 1) << 4);
    return *(const bf16x8*)(&lds[buf * 4 + h][e]);
  };
  auto rdB = [&](int buf, int h, int j, int kk) -> bf16x8 {
    const int row = wx * 32 + j * 16 + fc;
    const int e = (row * 64 + kk * 32 + fr * 8) ^ (((row >> 2) & 1) << 4);
    return *(const bf16x8*)(&lds[buf * 4 + 2 + h][e]);
  };

  f32x4 acc[4][4][2] = {};   // [quadrant pp][i][j]

  // prologue: tile0 fully, tile1 first halves
  stage(0, 0, 0, 0);  // b0.Ah0
  stage(2, 1, 0, 0);  // b0.Bh0
  stage(1, 0, 1, 0);  // b0.Ah1
  stage(3, 1, 1, 0);  // b0.Bh1
  stage(4, 0, 0, 1);  // b1.Ah0
  stage(6, 1, 0, 1);  // b1.Bh0
  VMCNT(4);           // tile0 (8 oldest loads) landed
  sbar();

  for (int t = 0; t < 16; ++t) {
    const int t2 = 2 * t;
    const bool notlast = (t < 15);
#pragma unroll
    for (int hv = 0; hv < 2; ++hv) {       // tile 2t+hv, buf = hv
      const int buf = hv;
#pragma unroll
      for (int pp = 0; pp < 4; ++pp) {
        const int mq = pp >> 1, nq = pp & 1;
        bf16x8 af[4][2], bv[2][2];
#pragma unroll
        for (int i = 0; i < 4; ++i)
#pragma unroll
          for (int kk = 0; kk < 2; ++kk) af[i][kk] = rdA(buf, mq, i, kk);
#pragma unroll
        for (int j = 0; j < 2; ++j)
#pragma unroll
          for (int kk = 0; kk < 2; ++kk) bv[j][kk] = rdB(buf, nq, j, kk);

        const int p = hv * 4 + pp;
        if (p == 0)        stage(5, 0, 1, t2 + 1);
        else if (p == 1)   stage(7, 1, 1, t2 + 1);
        else if (notlast) {
          if (p == 2)      stage(0, 0, 0, t2 + 2);
          else if (p == 3) stage(2, 1, 0, t2 + 2);
          else if (p == 4) stage(1, 0, 1, t2 + 2);
          else if (p == 5) stage(3, 1, 1, t2 + 2);
          else if (p == 6) stage(4, 0, 0, t2 + 3);
          else             stage(6, 1, 0, t2 + 3);
        }
        sbar();
        __builtin_amdgcn_s_setprio(1);
#pragma unroll
        for (int i = 0; i < 4; ++i)
#pragma unroll
          for (int j = 0; j < 2; ++j)
#pragma unroll
            for (int kk = 0; kk < 2; ++kk)
              acc[pp][i][j] = __builtin_amdgcn_mfma_f32_16x16x32_bf16(
                  af[i][kk], bv[j][kk], acc[pp][i][j], 0, 0, 0);
        __builtin_amdgcn_s_setprio(0);
        if (pp == 3) {
          if (hv == 0) {
            if (notlast) { VMCNT(4); } else { VMCNT(0); }
          } else {
            if (notlast) { VMCNT(4); }
          }
        }
        sbar();
      }
    }
  }

  // full fence before LDS reuse (epilogue scratch aliases slots 0/1)
  __syncthreads();

  // ---- epilogue: relu+bias store, per-row stats (4 x 128-col partials) ----
  float* sls = (float*)&lds[0][0];   // [256 rows][4 wx][2 nq][2 comp] = 16KB
  float bvv[2][2];
#pragma unroll
  for (int nq = 0; nq < 2; ++nq)
#pragma unroll
    for (int j = 0; j < 2; ++j)
      bvv[nq][j] = bias[nblk * 256 + nq * 128 + wx * 32 + j * 16 + fc];

#pragma unroll
  for (int q = 0; q < 4; ++q) {
    const int mq = q >> 1, nq = q & 1;
#pragma unroll
    for (int i = 0; i < 4; ++i) {
#pragma unroll
      for (int r = 0; r < 4; ++r) {
        const int row_l = mq * 128 + wy * 64 + i * 16 + fr * 4 + r;
        const int m = m0 + row_l;
        float v0 = acc[q][i][0][r] + bvv[nq][0]; v0 = v0 > 0.f ? v0 : 0.f;
        float v1 = acc[q][i][1][r] + bvv[nq][1]; v1 = v1 > 0.f ? v1 : 0.f;
        const int64_t cb = (int64_t)m * 1024 + z * 512
                           + nblk * 256 + nq * 128 + wx * 32 + fc;
        C[cb] = v0;
        C[cb + 16] = v1;
        float s1 = v0 + v1, s2 = v0 * v0 + v1 * v1;
#pragma unroll
        for (int o = 1; o < 16; o <<= 1) {
          s1 += __shfl_xor(s1, o);
          s2 += __shfl_xor(s2, o);
        }
        if (fc == 0) {
          sls[(row_l * 4 + wx) * 4 + nq * 2 + 0] = s1;
          sls[(row_l * 4 + wx) * 4 + nq * 2 + 1] = s2;
        }
      }
    }
  }
  __syncthreads();
  {
    const int row = tid >> 1, comp = tid & 1;
#pragma unroll
    for (int nq = 0; nq < 2; ++nq) {
      float v = 0.f;
#pragma unroll
      for (int wxx = 0; wxx < 4; ++wxx)
        v += sls[(row * 4 + wxx) * 4 + nq * 2 + comp];
      P[(((int64_t)z * 4 + nblk * 2 + nq) * Mx + m0 + row) * 2 + comp] = v;
    }
  }
}

// ---------------------------------------------------------------------------
// GEMM (consumer modes), round-0 structure: 128x128 tile, BK=32, 4 waves.
// MODE 2: v = C[..] + acc + bias; C[..] = v; out0p[s*16384+b*1024+z*512+n] = v
// STATS: per-row (sum, sumsq) of v -> P[(z*4+nb)*M + m][2]  (non-atomic)
// ---------------------------------------------------------------------------
template <int MODE, bool STATS>
__global__ __launch_bounds__(256) void gemm_k(
    const unsigned short* __restrict__ A0, const unsigned short* __restrict__ A1,
    int64_t a_bstride, int a_off_per_z, int K,
    const unsigned short* __restrict__ Bt0, const unsigned short* __restrict__ Bt1,
    const float* __restrict__ bias0, const float* __restrict__ bias1,
    float* __restrict__ C, float* __restrict__ out0p, float* __restrict__ P) {
  __shared__ unsigned short sA[128 * 32];
  __shared__ unsigned short sB[128 * 32];
  __shared__ float sls[128][2][2];
  const int tid  = threadIdx.x;
  const int lane = tid & 63;
  const int wave = tid >> 6;
  const int m0 = blockIdx.x * 128;
  const int n0 = blockIdx.y * 128;
  const int z  = blockIdx.z;
  const int wm = (wave >> 1) * 64;
  const int wn = (wave & 1) * 64;
  const int fr = lane >> 4;
  const int fc = lane & 15;

  const unsigned short* A  = z ? A1 : A0;
  const unsigned short* Bt = z ? Bt1 : Bt0;
  const float* bias = z ? bias1 : bias0;
  const int a_off = z * a_off_per_z;
  const int c_off = z * 512;

  const unsigned short* Ablk =
      A + (int64_t)(m0 >> 11) * a_bstride + (int64_t)(m0 & 2047) * 512 + a_off;
  const unsigned short* Bblk = Bt + (int64_t)n0 * K;

  f32x4 acc[4][4] = {};

  const int t0 = tid, t1 = tid + 256;
  const int ar0 = t0 >> 2, ac0 = (t0 & 3) * 8;
  const int ar1 = t1 >> 2, ac1 = (t1 & 3) * 8;

  for (int k0 = 0; k0 < K; k0 += 32) {
    __builtin_amdgcn_global_load_lds(
        (gvoid_t*)(Ablk + (int64_t)ar0 * 512 + k0 + ac0),
        (lvoid_t*)(sA + t0 * 8), 16, 0, 0);
    __builtin_amdgcn_global_load_lds(
        (gvoid_t*)(Ablk + (int64_t)ar1 * 512 + k0 + ac1),
        (lvoid_t*)(sA + t1 * 8), 16, 0, 0);
    __builtin_amdgcn_global_load_lds(
        (gvoid_t*)(Bblk + (int64_t)ar0 * K + k0 + ac0),
        (lvoid_t*)(sB + t0 * 8), 16, 0, 0);
    __builtin_amdgcn_global_load_lds(
        (gvoid_t*)(Bblk + (int64_t)ar1 * K + k0 + ac1),
        (lvoid_t*)(sB + t1 * 8), 16, 0, 0);
    __syncthreads();

    bf16x8 af[4], bf[4];
#pragma unroll
    for (int i = 0; i < 4; i++)
      af[i] = *(const bf16x8*)(sA + (wm + i * 16 + fc) * 32 + fr * 8);
#pragma unroll
    for (int j = 0; j < 4; j++)
      bf[j] = *(const bf16x8*)(sB + (wn + j * 16 + fc) * 32 + fr * 8);
#pragma unroll
    for (int i = 0; i < 4; i++)
#pragma unroll
      for (int j = 0; j < 4; j++)
        acc[i][j] = __builtin_amdgcn_mfma_f32_16x16x32_bf16(af[i], bf[j], acc[i][j], 0, 0, 0);
    __syncthreads();
  }

  int col[4];
  float bv[4];
#pragma unroll
  for (int j = 0; j < 4; j++) {
    col[j] = n0 + wn + j * 16 + fc;
    bv[j] = bias[col[j]];
  }
  const int b_idx = m0 >> 11;
#pragma unroll
  for (int i = 0; i < 4; i++) {
#pragma unroll
    for (int r = 0; r < 4; r++) {
      const int m = m0 + wm + i * 16 + fr * 4 + r;
      const int64_t base = (int64_t)m * 1024 + c_off;
      float vs[4];
      if (MODE == 0) {
#pragma unroll
        for (int j = 0; j < 4; j++) {
          float v = acc[i][j][r] + bv[j];
          v = v > 0.f ? v : 0.f;
          C[base + col[j]] = v;
          vs[j] = v;
        }
      } else {
        const int s = m & 2047;
        const int64_t obase = (int64_t)s * 16384 + (int64_t)b_idx * 1024 + c_off;
#pragma unroll
        for (int j = 0; j < 4; j++) {
          float v = C[base + col[j]] + acc[i][j][r] + bv[j];
          C[base + col[j]] = v;
          out0p[obase + col[j]] = v;
          vs[j] = v;
        }
      }
      if (STATS) {
        float s1 = vs[0] + vs[1] + vs[2] + vs[3];
        float s2 = vs[0] * vs[0] + vs[1] * vs[1] + vs[2] * vs[2] + vs[3] * vs[3];
#pragma unroll
        for (int o = 1; o < 16; o <<= 1) {
          s1 += __shfl_xor(s1, o);
          s2 += __shfl_xor(s2, o);
        }
        if (fc == 0) {
          int li = (wave >> 1) * 64 + i * 16 + fr * 4 + r;
          sls[li][wave & 1][0] = s1;
          sls[li][wave & 1][1] = s2;
        }
      }
    }
  }
  if (STATS) {
    __syncthreads();
    int li = tid >> 1, comp = tid & 1;
    float v = sls[li][0][comp] + sls[li][1][comp];
    P[(((int64_t)z * 4 + blockIdx.y) * Mx + m0 + li) * 2 + comp] = v;
  }
}

// ---------------------------------------------------------------------------
// FF first GEMM with fused LayerNorm on A-load (round-0 structure, BK=32).
// ---------------------------------------------------------------------------
__global__ __launch_bounds__(256) void gemm_ln_k(
    const float* __restrict__ state, const float* __restrict__ P,
    const float* __restrict__ g0, const float* __restrict__ g1p,
    const float* __restrict__ be0, const float* __restrict__ be1,
    const unsigned short* __restrict__ Bt0, const unsigned short* __restrict__ Bt1,
    const float* __restrict__ bias0, const float* __restrict__ bias1,
    unsigned short* __restrict__ hidden) {
  __shared__ unsigned short sA[128 * 32];
  __shared__ unsigned short sB[128 * 32];
  const int tid  = threadIdx.x;
  const int lane = tid & 63;
  const int wave = tid >> 6;
  const int m0 = blockIdx.x * 128;
  const int n0 = blockIdx.y * 128;
  const int z  = blockIdx.z;
  const int wm = (wave >> 1) * 64;
  const int wn = (wave & 1) * 64;
  const int fr = lane >> 4;
  const int fc = lane & 15;

  const unsigned short* Bt = z ? Bt1 : Bt0;
  const float* bias = z ? bias1 : bias0;
  const float* g    = z ? g1p : g0;
  const float* be   = z ? be1 : be0;
  const int c_off = z * 512;
  const unsigned short* Bblk = Bt + (int64_t)n0 * 512;

  const int row  = tid >> 1;
  const int half = tid & 1;
  const int m = m0 + row;
  const float* srcrow = state + (int64_t)m * 1024 + c_off + half * 16;

  float s1 = 0.f, s2 = 0.f;
#pragma unroll
  for (int nb = 0; nb < 4; nb++) {
    s1 += P[(((int64_t)z * 4 + nb) * Mx + m) * 2 + 0];
    s2 += P[(((int64_t)z * 4 + nb) * Mx + m) * 2 + 1];
  }
  const float mean = s1 * (1.0f / 512.0f);
  const float rstd = rsqrtf(s2 * (1.0f / 512.0f) - mean * mean + 1e-5f);

  f32x4 acc[4][4] = {};

  const int t0 = tid, t1 = tid + 256;
  const int br0 = t0 >> 2, bc0 = (t0 & 3) * 8;
  const int br1 = t1 >> 2, bc1 = (t1 & 3) * 8;

  for (int k0 = 0; k0 < 512; k0 += 32) {
    __builtin_amdgcn_global_load_lds(
        (gvoid_t*)(Bblk + (int64_t)br0 * 512 + k0 + bc0),
        (lvoid_t*)(sB + t0 * 8), 16, 0, 0);
    __builtin_amdgcn_global_load_lds(
        (gvoid_t*)(Bblk + (int64_t)br1 * 512 + k0 + bc1),
        (lvoid_t*)(sB + t1 * 8), 16, 0, 0);

    const float* sp = srcrow + k0;
    float xs[16], gs[16], bs[16];
    *(float4*)(xs + 0)  = ((const float4*)sp)[0];
    *(float4*)(xs + 4)  = ((const float4*)sp)[1];
    *(float4*)(xs + 8)  = ((const float4*)sp)[2];
    *(float4*)(xs + 12) = ((const float4*)sp)[3];
    const float* gp = g + k0 + half * 16;
    const float* bp = be + k0 + half * 16;
    *(float4*)(gs + 0)  = ((const float4*)gp)[0];
    *(float4*)(gs + 4)  = ((const float4*)gp)[1];
    *(float4*)(gs + 8)  = ((const float4*)gp)[2];
    *(float4*)(gs + 12) = ((const float4*)gp)[3];
    *(float4*)(bs + 0)  = ((const float4*)bp)[0];
    *(float4*)(bs + 4)  = ((const float4*)bp)[1];
    *(float4*)(bs + 8)  = ((const float4*)bp)[2];
    *(float4*)(bs + 12) = ((const float4*)bp)[3];
    u16x8 o0, o1;
#pragma unroll
    for (int t = 0; t < 8; t++)
      o0[t] = f2bf((xs[t] - mean) * rstd * gs[t] + bs[t]);
#pragma unroll
    for (int t = 0; t < 8; t++)
      o1[t] = f2bf((xs[t + 8] - mean) * rstd * gs[t + 8] + bs[t + 8]);
    *(u16x8*)(sA + row * 32 + half * 16)     = o0;
    *(u16x8*)(sA + row * 32 + half * 16 + 8) = o1;
    __syncthreads();

    bf16x8 af[4], bf[4];
#pragma unroll
    for (int i = 0; i < 4; i++)
      af[i] = *(const bf16x8*)(sA + (wm + i * 16 + fc) * 32 + fr * 8);
#pragma unroll
    for (int j = 0; j < 4; j++)
      bf[j] = *(const bf16x8*)(sB + (wn + j * 16 + fc) * 32 + fr * 8);
#pragma unroll
    for (int i = 0; i < 4; i++)
#pragma unroll
      for (int j = 0; j < 4; j++)
        acc[i][j] = __builtin_amdgcn_mfma_f32_16x16x32_bf16(af[i], bf[j], acc[i][j], 0, 0, 0);
    __syncthreads();
  }

  unsigned short* Cb = hidden + (int64_t)z * Mx * 512;
  int col[4];
  float bv[4];
#pragma unroll
  for (int j = 0; j < 4; j++) {
    col[j] = n0 + wn + j * 16 + fc;
    bv[j] = bias[col[j]];
  }
#pragma unroll
  for (int i = 0; i < 4; i++) {
#pragma unroll
    for (int r = 0; r < 4; r++) {
      const int mm = m0 + wm + i * 16 + fr * 4 + r;
      const int64_t base = (int64_t)mm * 512;
#pragma unroll
      for (int j = 0; j < 4; j++) {
        float v = acc[i][j][r] + bv[j];
        Cb[base + col[j]] = f2bf(v > 0.f ? v : 0.f);
      }
    }
  }
}

// ---------------------------------------------------------------------------
extern "C" void kernel_launch(void* const* d_in, const int* in_sizes, int n_in,
                              void* d_out, int out_size, void* d_ws, size_t ws_size,
                              hipStream_t stream) {
  const float* inputs = (const float*)d_in[0];
  const float* lp     = (const float*)d_in[1];
  const float* rp     = (const float*)d_in[2];
  const float* Wl     = (const float*)d_in[3];
  const float* bl     = (const float*)d_in[4];
  const float* Wr     = (const float*)d_in[5];
  const float* br     = (const float*)d_in[6];
  const float* lw1    = (const float*)d_in[7];
  const float* lb1    = (const float*)d_in[8];
  const float* lw2    = (const float*)d_in[9];
  const float* lb2    = (const float*)d_in[10];
  const float* lg     = (const float*)d_in[11];
  const float* lbeta  = (const float*)d_in[12];
  const float* rw1    = (const float*)d_in[13];
  const float* rb1    = (const float*)d_in[14];
  const float* rw2    = (const float*)d_in[15];
  const float* rb2    = (const float*)d_in[16];
  const float* rg     = (const float*)d_in[17];
  const float* rbeta  = (const float*)d_in[18];

  float* out0 = (float*)d_out;                              // all_layers [L,S,B,2H]
  float* out1 = out0 + (int64_t)Lx * Sx * Bx * 1024;        // last_layers (lo/ro state)

  char* w = (char*)d_ws;
  auto take = [&](size_t n) { char* p = w; w += (n + 255) & ~(size_t)255; return p; };
  unsigned short* padded = (unsigned short*)take((size_t)Bx * PHx * Hx * 2);
  unsigned short* Wlt    = (unsigned short*)take(2048ull * 512 * 2);
  unsigned short* Wrt    = (unsigned short*)take(2048ull * 512 * 2);
  unsigned short* lw1t   = (unsigned short*)take((size_t)Lx * 512 * 512 * 2);
  unsigned short* lw2t   = (unsigned short*)take((size_t)Lx * 512 * 512 * 2);
  unsigned short* rw1t   = (unsigned short*)take((size_t)Lx * 512 * 512 * 2);
  unsigned short* rw2t   = (unsigned short*)take((size_t)Lx * 512 * 512 * 2);
  unsigned short* hidden = (unsigned short*)take((size_t)2 * Mx * 512 * 2);
  float*          Pst    = (float*)take((size_t)2 * 4 * Mx * 2 * 4);

  build_padded_k<<<8224, 256, 0, stream>>>(inputs, lp, rp, padded);
  prep_weights_k<<<4096, 256, 0, stream>>>(Wl, Wr, lw1, lw2, rw1, rw2,
                                           Wlt, Wrt, lw1t, lw2t, rw1t, rw2t);

  // projection: 8-phase 256x256 schedule
  proj8_k<<<dim3(128, 2, 2), 512, 0, stream>>>(
      padded, Wlt, Wrt, bl, br, out1, Pst);

  for (int i = 0; i < Lx; i++) {
    gemm_ln_k<<<dim3(256, 4, 2), 256, 0, stream>>>(
        out1, Pst, lg + i * 512, rg + i * 512, lbeta + i * 512, rbeta + i * 512,
        lw1t + (int64_t)i * 262144, rw1t + (int64_t)i * 262144,
        lb1 + i * 512, rb1 + i * 512, hidden);
    if (i == 0) {
      gemm_k<2, true><<<dim3(256, 4, 2), 256, 0, stream>>>(
          hidden, hidden + (int64_t)Mx * 512, (int64_t)2048 * 512, 0, 512,
          lw2t, rw2t, lb2, rb2, out1, out0, Pst);
    } else {
      gemm_k<2, false><<<dim3(256, 4, 2), 256, 0, stream>>>(
          hidden, hidden + (int64_t)Mx * 512, (int64_t)2048 * 512, 0, 512,
          lw2t + (int64_t)i * 262144, rw2t + (int64_t)i * 262144,
          lb2 + i * 512, rb2 + i * 512, out1,
          out0 + (int64_t)i * Sx * Bx * 1024, nullptr);
    }
  }
}

// Round 6
// 1010.914 us; speedup vs baseline: 1.1583x; 1.0683x over previous
//
#include <hip/hip_runtime.h>
#include <stdint.h>

// Problem constants (B,S,H,W,L) = (16,2048,512,4,2)
#define Bx   16
#define Sx   2048
#define Hx   512
#define Lx   2
#define PHx  2056            // S + 2W
#define Mx   32768           // B*S

typedef float f32x4  __attribute__((ext_vector_type(4)));
typedef __bf16 bf16x8 __attribute__((ext_vector_type(8)));
typedef unsigned short u16x8 __attribute__((ext_vector_type(8)));

typedef __attribute__((address_space(1))) void gvoid_t;
typedef __attribute__((address_space(3))) void lvoid_t;

__device__ __forceinline__ unsigned short f2bf(float f) {
  uint32_t u = __float_as_uint(f);
  u += 0x7FFFu + ((u >> 16) & 1u);   // round-to-nearest-even
  return (unsigned short)(u >> 16);
}

// LDS granule swizzle (BK=32 tiles, 64B rows): logical granule g (of 4 x 8
// bf16) of row r lives in LDS slot g ^ (r&3). Fixes the 8-way frag-read
// conflict (fc lanes alternate banks 0/16) down to 4-way. Applied both-sides:
// DMA dest stays linear, global SOURCE granule is pre-swizzled (rule #21);
// VGPR-staged writes swizzle the ds_write address; reads swizzle the slot.

// ---------------------------------------------------------------------------
// padded[b, r, h]: r<4 -> left_padding, 4..2051 -> inputs, 2052..2055 -> right
// ---------------------------------------------------------------------------
__global__ __launch_bounds__(256) void build_padded_k(
    const float* __restrict__ inp, const float* __restrict__ lp,
    const float* __restrict__ rp, unsigned short* __restrict__ padded) {
  int64_t idx = ((int64_t)blockIdx.x * 256 + threadIdx.x) * 8;  // < 16*2056*512
  int h = (int)(idx & 511);
  int64_t rowi = idx >> 9;                 // b*2056 + r
  int r = (int)(rowi % 2056);
  int b = (int)(rowi / 2056);
  const float* src;
  if (r < 4)          src = lp + r * 512 + h;
  else if (r < 2052)  src = inp + ((int64_t)b * 2048 + (r - 4)) * 512 + h;
  else                src = rp + (r - 2052) * 512 + h;
  float4 u = ((const float4*)src)[0];
  float4 w = ((const float4*)src)[1];
  u16x8 o;
  o[0] = f2bf(u.x); o[1] = f2bf(u.y); o[2] = f2bf(u.z); o[3] = f2bf(u.w);
  o[4] = f2bf(w.x); o[5] = f2bf(w.y); o[6] = f2bf(w.z); o[7] = f2bf(w.w);
  *(u16x8*)(padded + idx) = o;
}

// ---------------------------------------------------------------------------
// Weight prep: bf16 [N][K] transpose via LDS 32x32 tiles.
// ---------------------------------------------------------------------------
__global__ __launch_bounds__(256) void prep_weights_k(
    const float* __restrict__ Wl, const float* __restrict__ Wr,
    const float* __restrict__ lw1, const float* __restrict__ lw2,
    const float* __restrict__ rw1, const float* __restrict__ rw2,
    unsigned short* __restrict__ Wlt, unsigned short* __restrict__ Wrt,
    unsigned short* __restrict__ lw1t, unsigned short* __restrict__ lw2t,
    unsigned short* __restrict__ rw1t, unsigned short* __restrict__ rw2t) {
  __shared__ unsigned short tl[32][36];
  int b = blockIdx.x;
  const float* src; unsigned short* dst; int K, tk, tn;
  if (b < 2048) {
    src = (b < 1024) ? Wl : Wr;
    dst = (b < 1024) ? Wlt : Wrt;
    int t = b & 1023; tk = t >> 4; tn = t & 15; K = 2048;
  } else {
    int b2 = b - 2048;
    int mat = b2 >> 8;  // 0..7
    const float* srcs[8] = {lw1, lw1 + 262144, lw2, lw2 + 262144,
                            rw1, rw1 + 262144, rw2, rw2 + 262144};
    unsigned short* dsts[8] = {lw1t, lw1t + 262144, lw2t, lw2t + 262144,
                               rw1t, rw1t + 262144, rw2t, rw2t + 262144};
    src = srcs[mat]; dst = dsts[mat];
    int tt = b2 & 255; tk = tt >> 4; tn = tt & 15; K = 512;
  }
  int t = threadIdx.x;
  int rr = t >> 3, c4 = (t & 7) * 4;
  float4 v = *(const float4*)(src + (int64_t)(tk * 32 + rr) * 512 + tn * 32 + c4);
  tl[c4 + 0][rr] = f2bf(v.x);
  tl[c4 + 1][rr] = f2bf(v.y);
  tl[c4 + 2][rr] = f2bf(v.z);
  tl[c4 + 3][rr] = f2bf(v.w);
  __syncthreads();
  int nn = t >> 3, k4 = (t & 7) * 4;
  ushort4 o = {tl[nn][k4], tl[nn][k4 + 1], tl[nn][k4 + 2], tl[nn][k4 + 3]};
  *(ushort4*)(dst + (int64_t)(tn * 32 + nn) * K + tk * 32 + k4) = o;
}

// ---------------------------------------------------------------------------
// GEMM (DMA-staged): C[M, 512 cols of side z] = epilogue(A @ Bt^T + bias).
// BM=256 x BN=128, BK=32, 512 threads (8 waves, 4My x 2Nx), 2-phase dbuf:
//   stage(t+1 -> buf^1) issued BEFORE compute(t); one __syncthreads per step.
// grid (Mx/256, 4, 2). 4-way granule swizzle on LDS tiles (see top).
// MODE 0: v = relu(acc+bias); C[m*1024 + z*512 + n] = v       (projection)
// MODE 2: v = C[..] + acc + bias; C[..] = v; out0p[s*16384+b*1024+z*512+n] = v
// STATS: per-row (sum, sumsq) of v -> P[(z*4+nb)*M + m][2]  (non-atomic)
// ---------------------------------------------------------------------------
template <int MODE, bool STATS>
__global__ __launch_bounds__(512) void gemm_k(
    const unsigned short* __restrict__ A0, const unsigned short* __restrict__ A1,
    int64_t a_bstride, int a_off_per_z, int K,
    const unsigned short* __restrict__ Bt0, const unsigned short* __restrict__ Bt1,
    const float* __restrict__ bias0, const float* __restrict__ bias1,
    float* __restrict__ C, float* __restrict__ out0p, float* __restrict__ P) {
  __shared__ unsigned short sA[2][256 * 32];
  __shared__ unsigned short sB[2][128 * 32];
  __shared__ float sls[256][2][2];
  const int tid  = threadIdx.x;
  const int lane = tid & 63;
  const int wave = tid >> 6;          // 0..7
  const int m0 = blockIdx.x * 256;
  const int n0 = blockIdx.y * 128;
  const int z  = blockIdx.z;
  const int wm = (wave >> 1) * 64;    // 0,64,128,192
  const int wn = (wave & 1) * 64;     // 0,64
  const int fr = lane >> 4;
  const int fc = lane & 15;
  const int swA = ((fr ^ (fc & 3)) << 3);   // frag-read swizzle (elem offset)

  const unsigned short* A  = z ? A1 : A0;
  const unsigned short* Bt = z ? Bt1 : Bt0;
  const float* bias = z ? bias1 : bias0;
  const int a_off = z * a_off_per_z;
  const int c_off = z * 512;

  const unsigned short* Ablk =
      A + (int64_t)(m0 >> 11) * a_bstride + (int64_t)(m0 & 2047) * 512 + a_off;
  const unsigned short* Bblk = Bt + (int64_t)n0 * K;

  f32x4 acc[4][4] = {};

  // staging: A = 1024 chunks (tid, tid+512), B = 512 chunks (tid)
  auto stage = [&](int k0, int buf) {
#pragma unroll
    for (int L = 0; L < 2; ++L) {
      const int id = tid + L * 512;
      const int row = id >> 2, g = id & 3;
      const int sc = (g ^ (row & 3)) * 8;     // pre-swizzled source granule
      __builtin_amdgcn_global_load_lds(
          (gvoid_t*)(Ablk + (int64_t)row * 512 + k0 + sc),
          (lvoid_t*)(&sA[buf][id * 8]), 16, 0, 0);
    }
    {
      const int row = tid >> 2, g = tid & 3;
      const int sc = (g ^ (row & 3)) * 8;
      __builtin_amdgcn_global_load_lds(
          (gvoid_t*)(Bblk + (int64_t)row * K + k0 + sc),
          (lvoid_t*)(&sB[buf][tid * 8]), 16, 0, 0);
    }
  };

  stage(0, 0);
  __syncthreads();

  int buf = 0;
  for (int k0 = 0; k0 < K; k0 += 32) {
    if (k0 + 32 < K) stage(k0 + 32, buf ^ 1);

    bf16x8 af[4], bf[4];
#pragma unroll
    for (int i = 0; i < 4; i++)
      af[i] = *(const bf16x8*)(&sA[buf][(wm + i * 16 + fc) * 32 + swA]);
#pragma unroll
    for (int j = 0; j < 4; j++)
      bf[j] = *(const bf16x8*)(&sB[buf][(wn + j * 16 + fc) * 32 + swA]);
#pragma unroll
    for (int i = 0; i < 4; i++)
#pragma unroll
      for (int j = 0; j < 4; j++)
        acc[i][j] = __builtin_amdgcn_mfma_f32_16x16x32_bf16(af[i], bf[j], acc[i][j], 0, 0, 0);
    __syncthreads();
    buf ^= 1;
  }

  // epilogue: acc[i][j][r] -> row m0+wm+i*16+fr*4+r, col n0+wn+j*16+fc
  int col[4];
  float bv[4];
#pragma unroll
  for (int j = 0; j < 4; j++) {
    col[j] = n0 + wn + j * 16 + fc;
    bv[j] = bias[col[j]];
  }
  const int b_idx = m0 >> 11;
#pragma unroll
  for (int i = 0; i < 4; i++) {
#pragma unroll
    for (int r = 0; r < 4; r++) {
      const int m = m0 + wm + i * 16 + fr * 4 + r;
      const int64_t base = (int64_t)m * 1024 + c_off;
      float vs[4];
      if (MODE == 0) {
#pragma unroll
        for (int j = 0; j < 4; j++) {
          float v = acc[i][j][r] + bv[j];
          v = v > 0.f ? v : 0.f;
          C[base + col[j]] = v;
          vs[j] = v;
        }
      } else {
        const int s = m & 2047;
        const int64_t obase = (int64_t)s * 16384 + (int64_t)b_idx * 1024 + c_off;
#pragma unroll
        for (int j = 0; j < 4; j++) {
          float v = C[base + col[j]] + acc[i][j][r] + bv[j];
          C[base + col[j]] = v;
          out0p[obase + col[j]] = v;
          vs[j] = v;
        }
      }
      if (STATS) {
        float s1 = vs[0] + vs[1] + vs[2] + vs[3];
        float s2 = vs[0] * vs[0] + vs[1] * vs[1] + vs[2] * vs[2] + vs[3] * vs[3];
#pragma unroll
        for (int o = 1; o < 16; o <<= 1) {
          s1 += __shfl_xor(s1, o);
          s2 += __shfl_xor(s2, o);
        }
        if (fc == 0) {
          int li = wm + i * 16 + fr * 4 + r;      // 0..255
          sls[li][wave & 1][0] = s1;
          sls[li][wave & 1][1] = s2;
        }
      }
    }
  }
  if (STATS) {
    __syncthreads();
    int li = tid >> 1, comp = tid & 1;
    float v = sls[li][0][comp] + sls[li][1][comp];
    P[(((int64_t)z * 4 + blockIdx.y) * Mx + m0 + li) * 2 + comp] = v;
  }
}

// ---------------------------------------------------------------------------
// FF first GEMM with fused LayerNorm on A-load:
// hidden[z][m][n] = relu( LN(state_row_m, side z) @ w1^T + b1 )
// BM=128 x BN=128, BK=32, 256 threads, 2-phase dbuf (B via DMA, A via VGPR
// LN staging with swizzled ds_write). grid (Mx/128, 4, 2).
// ---------------------------------------------------------------------------
__global__ __launch_bounds__(256) void gemm_ln_k(
    const float* __restrict__ state, const float* __restrict__ P,
    const float* __restrict__ g0, const float* __restrict__ g1p,
    const float* __restrict__ be0, const float* __restrict__ be1,
    const unsigned short* __restrict__ Bt0, const unsigned short* __restrict__ Bt1,
    const float* __restrict__ bias0, const float* __restrict__ bias1,
    unsigned short* __restrict__ hidden) {
  __shared__ unsigned short sA[2][128 * 32];
  __shared__ unsigned short sB[2][128 * 32];
  const int tid  = threadIdx.x;
  const int lane = tid & 63;
  const int wave = tid >> 6;
  const int m0 = blockIdx.x * 128;
  const int n0 = blockIdx.y * 128;
  const int z  = blockIdx.z;
  const int wm = (wave >> 1) * 64;
  const int wn = (wave & 1) * 64;
  const int fr = lane >> 4;
  const int fc = lane & 15;
  const int swA = ((fr ^ (fc & 3)) << 3);

  const unsigned short* Bt = z ? Bt1 : Bt0;
  const float* bias = z ? bias1 : bias0;
  const float* g    = z ? g1p : g0;
  const float* be   = z ? be1 : be0;
  const int c_off = z * 512;
  const unsigned short* Bblk = Bt + (int64_t)n0 * 512;

  // A-staging mapping: thread -> (row, 16-col half)
  const int row  = tid >> 1;
  const int half = tid & 1;
  const int m = m0 + row;
  const float* srcrow = state + (int64_t)m * 1024 + c_off + half * 16;
  // swizzled ds_write dests for the two granules (half*2, half*2+1)
  const int d0 = row * 32 + (((half * 2 + 0) ^ (row & 3)) << 3);
  const int d1 = row * 32 + (((half * 2 + 1) ^ (row & 3)) << 3);

  // row stats: combine 4 n-block partials
  float s1 = 0.f, s2 = 0.f;
#pragma unroll
  for (int nb = 0; nb < 4; nb++) {
    s1 += P[(((int64_t)z * 4 + nb) * Mx + m) * 2 + 0];
    s2 += P[(((int64_t)z * 4 + nb) * Mx + m) * 2 + 1];
  }
  const float mean = s1 * (1.0f / 512.0f);
  const float rstd = rsqrtf(s2 * (1.0f / 512.0f) - mean * mean + 1e-5f);

  auto stageB = [&](int k0, int buf) {
#pragma unroll
    for (int L = 0; L < 2; ++L) {
      const int id = tid + L * 256;
      const int br = id >> 2, bg = id & 3;
      const int sc = (bg ^ (br & 3)) * 8;
      __builtin_amdgcn_global_load_lds(
          (gvoid_t*)(Bblk + (int64_t)br * 512 + k0 + sc),
          (lvoid_t*)(&sB[buf][id * 8]), 16, 0, 0);
    }
  };
  auto stageA = [&](int k0, int buf) {
    const float* sp = srcrow + k0;
    const float* gp = g + k0 + half * 16;
    const float* bp = be + k0 + half * 16;
#pragma unroll
    for (int c = 0; c < 2; ++c) {
      float xs[8], gs[8], bs[8];
      *(float4*)(xs + 0) = ((const float4*)sp)[c * 2 + 0];
      *(float4*)(xs + 4) = ((const float4*)sp)[c * 2 + 1];
      *(float4*)(gs + 0) = ((const float4*)gp)[c * 2 + 0];
      *(float4*)(gs + 4) = ((const float4*)gp)[c * 2 + 1];
      *(float4*)(bs + 0) = ((const float4*)bp)[c * 2 + 0];
      *(float4*)(bs + 4) = ((const float4*)bp)[c * 2 + 1];
      u16x8 o;
#pragma unroll
      for (int t = 0; t < 8; t++)
        o[t] = f2bf((xs[t] - mean) * rstd * gs[t] + bs[t]);
      *(u16x8*)(&sA[buf][c == 0 ? d0 : d1]) = o;
    }
  };

  f32x4 acc[4][4] = {};

  stageB(0, 0);
  stageA(0, 0);
  __syncthreads();

  int buf = 0;
  for (int k0 = 0; k0 < 512; k0 += 32) {
    if (k0 + 32 < 512) {
      stageB(k0 + 32, buf ^ 1);
      stageA(k0 + 32, buf ^ 1);
    }

    bf16x8 af[4], bf[4];
#pragma unroll
    for (int i = 0; i < 4; i++)
      af[i] = *(const bf16x8*)(&sA[buf][(wm + i * 16 + fc) * 32 + swA]);
#pragma unroll
    for (int j = 0; j < 4; j++)
      bf[j] = *(const bf16x8*)(&sB[buf][(wn + j * 16 + fc) * 32 + swA]);
#pragma unroll
    for (int i = 0; i < 4; i++)
#pragma unroll
      for (int j = 0; j < 4; j++)
        acc[i][j] = __builtin_amdgcn_mfma_f32_16x16x32_bf16(af[i], bf[j], acc[i][j], 0, 0, 0);
    __syncthreads();
    buf ^= 1;
  }

  unsigned short* Cb = hidden + (int64_t)z * Mx * 512;
  int col[4];
  float bv[4];
#pragma unroll
  for (int j = 0; j < 4; j++) {
    col[j] = n0 + wn + j * 16 + fc;
    bv[j] = bias[col[j]];
  }
#pragma unroll
  for (int i = 0; i < 4; i++) {
#pragma unroll
    for (int r = 0; r < 4; r++) {
      const int mm = m0 + wm + i * 16 + fr * 4 + r;
      const int64_t base = (int64_t)mm * 512;
#pragma unroll
      for (int j = 0; j < 4; j++) {
        float v = acc[i][j][r] + bv[j];
        Cb[base + col[j]] = f2bf(v > 0.f ? v : 0.f);
      }
    }
  }
}

// ---------------------------------------------------------------------------
extern "C" void kernel_launch(void* const* d_in, const int* in_sizes, int n_in,
                              void* d_out, int out_size, void* d_ws, size_t ws_size,
                              hipStream_t stream) {
  const float* inputs = (const float*)d_in[0];
  const float* lp     = (const float*)d_in[1];
  const float* rp     = (const float*)d_in[2];
  const float* Wl     = (const float*)d_in[3];
  const float* bl     = (const float*)d_in[4];
  const float* Wr     = (const float*)d_in[5];
  const float* br     = (const float*)d_in[6];
  const float* lw1    = (const float*)d_in[7];
  const float* lb1    = (const float*)d_in[8];
  const float* lw2    = (const float*)d_in[9];
  const float* lb2    = (const float*)d_in[10];
  const float* lg     = (const float*)d_in[11];
  const float* lbeta  = (const float*)d_in[12];
  const float* rw1    = (const float*)d_in[13];
  const float* rb1    = (const float*)d_in[14];
  const float* rw2    = (const float*)d_in[15];
  const float* rb2    = (const float*)d_in[16];
  const float* rg     = (const float*)d_in[17];
  const float* rbeta  = (const float*)d_in[18];

  float* out0 = (float*)d_out;                              // all_layers [L,S,B,2H]
  float* out1 = out0 + (int64_t)Lx * Sx * Bx * 1024;        // last_layers (lo/ro state)

  char* w = (char*)d_ws;
  auto take = [&](size_t n) { char* p = w; w += (n + 255) & ~(size_t)255; return p; };
  unsigned short* padded = (unsigned short*)take((size_t)Bx * PHx * Hx * 2);
  unsigned short* Wlt    = (unsigned short*)take(2048ull * 512 * 2);
  unsigned short* Wrt    = (unsigned short*)take(2048ull * 512 * 2);
  unsigned short* lw1t   = (unsigned short*)take((size_t)Lx * 512 * 512 * 2);
  unsigned short* lw2t   = (unsigned short*)take((size_t)Lx * 512 * 512 * 2);
  unsigned short* rw1t   = (unsigned short*)take((size_t)Lx * 512 * 512 * 2);
  unsigned short* rw2t   = (unsigned short*)take((size_t)Lx * 512 * 512 * 2);
  unsigned short* hidden = (unsigned short*)take((size_t)2 * Mx * 512 * 2);
  float*          Pst    = (float*)take((size_t)2 * 4 * Mx * 2 * 4);

  build_padded_k<<<8224, 256, 0, stream>>>(inputs, lp, rp, padded);
  prep_weights_k<<<4096, 256, 0, stream>>>(Wl, Wr, lw1, lw2, rw1, rw2,
                                           Wlt, Wrt, lw1t, lw2t, rw1t, rw2t);

  // projections (z=0 left a_off=0, z=1 right a_off=2560), with LN stats
  gemm_k<0, true><<<dim3(128, 4, 2), 512, 0, stream>>>(
      padded, padded, (int64_t)PHx * 512, 5 * 512, 2048,
      Wlt, Wrt, bl, br, out1, nullptr, Pst);

  for (int i = 0; i < Lx; i++) {
    gemm_ln_k<<<dim3(256, 4, 2), 256, 0, stream>>>(
        out1, Pst, lg + i * 512, rg + i * 512, lbeta + i * 512, rbeta + i * 512,
        lw1t + (int64_t)i * 262144, rw1t + (int64_t)i * 262144,
        lb1 + i * 512, rb1 + i * 512, hidden);
    if (i == 0) {
      gemm_k<2, true><<<dim3(128, 4, 2), 512, 0, stream>>>(
          hidden, hidden + (int64_t)Mx * 512, (int64_t)2048 * 512, 0, 512,
          lw2t, rw2t, lb2, rb2, out1, out0, Pst);
    } else {
      gemm_k<2, false><<<dim3(128, 4, 2), 512, 0, stream>>>(
          hidden, hidden + (int64_t)Mx * 512, (int64_t)2048 * 512, 0, 512,
          lw2t + (int64_t)i * 262144, rw2t + (int64_t)i * 262144,
          lb2 + i * 512, rb2 + i * 512, out1,
          out0 + (int64_t)i * Sx * Bx * 1024, nullptr);
    }
  }
}